// Round 8
// baseline (535.473 us; speedup 1.0000x reference)
//
#include <hip/hip_runtime.h>
#include <hip/hip_fp16.h>
#include <math.h>

// FBP adjoint as dense f16 MFMA GEMM with split-K.
//   out[b,i0,i1,i2] = (1/A) * sum_{j,k} W[(i0,i2),(j,k)] * x[b,j,i1,k]
// C[M=1089(n=i0*33+i2), N=4224(i1*128+b)] = W[MxK] . Xt[NxK]^T, K=3993->4032.
// R8: grid 297 -> 891 via 3-way K-split (occupancy was 10.7%, 1 block/CU —
// barrier drains fully exposed, MfmaUtil 12%). Partials accumulated with
// fp32 atomicAdd into out (zeroed via hipMemsetAsync). Block order
// (tileN, ks, tileM) so consecutive blocks share the Xt quarter-panel in L2.

#define PDIM 33
#define PP   1089
#define A_   121
#define K_   3993
#define KP   4032
#define MP   1152
#define BM   128
#define BN   128
#define BK   32
#define LDW  40              // LDS row stride (halves): 32 + 8 pad
#define MT   9               // M tiles
#define NT   33              // N tiles
#define KS   3               // K splits
#define KCH  1344            // K per split (multiple of BK)
#define OUTB 35937           // 33*33*33

typedef _Float16 f16x8 __attribute__((ext_vector_type(8)));
typedef float    f32x4 __attribute__((ext_vector_type(4)));

// ---------------- fast path kernels ----------------

__global__ __launch_bounds__(128)
void wfill_kernel(const float* __restrict__ angles, __half* __restrict__ W)
{
    const int n = blockIdx.x;            // 0..1151
    const int t = threadIdx.x;
    __half* row = W + (size_t)n * KP;
    for (int e = t; e < KP; e += 128) row[e] = __float2half_rn(0.0f);
    __syncthreads();
    if (n >= PP || t >= A_) return;
    const int j  = t;
    const int i0 = n / PDIM;
    const int i2 = n - i0 * PDIM;
    float s, c;
    sincosf(angles[j], &s, &c);
    float ix = fmaf((float)(i2 - 16), c, fmaf((float)(i0 - 16), s, 16.0f));
    float fl = floorf(ix);
    int   k0 = (int)fl;
    float w1 = ix - fl;
    float w0 = 1.0f - w1;
    __half* seg = row + j * PDIM;
    if (k0 >= 0     && k0 < PDIM)     seg[k0]     = __float2half_rn(w0);
    if (k0 + 1 >= 0 && k0 + 1 < PDIM) seg[k0 + 1] = __float2half_rn(w1);
}

__global__ __launch_bounds__(256)
void xt_kernel(const float* __restrict__ x, __half* __restrict__ Xt)
{
    const int n  = blockIdx.x;           // 0..4223
    const int i1 = n >> 7;
    const int b  = n & 127;
    const float* src = x + (size_t)b * (A_ * PP) + (size_t)i1 * PDIM;
    __half* dst = Xt + (size_t)n * KP;
    for (int e = threadIdx.x; e < KP; e += 256) {
        float v = 0.0f;
        if (e < K_) {
            int j = e / PDIM;
            int k = e - j * PDIM;
            v = src[(size_t)j * PP + k];
        }
        dst[e] = __float2half_rn(v);
    }
}

// GEMM: C += W . Xt^T over one K-chunk; 128x128 tile, 4 waves (2x2), 64x64/wave.
__global__ __launch_bounds__(256)
void gemm_kernel(const __half* __restrict__ W, const __half* __restrict__ Xt,
                 float* __restrict__ out, float invA)
{
    __shared__ _Float16 As[BM * LDW];    // 10 KB
    __shared__ _Float16 Bs[BN * LDW];    // 10 KB

    // blk = tileN*(KS*MT) + ks*MT + tileM : consecutive blocks share Xt panel.
    const int blk   = blockIdx.x;
    const int tileN = blk / (KS * MT);
    const int rem   = blk - tileN * (KS * MT);
    const int ks    = rem / MT;
    const int tileM = rem - ks * MT;

    const int t     = threadIdx.x;
    const int lane  = t & 63;
    const int wave  = t >> 6;
    const int warpM = wave >> 1;
    const int warpN = wave & 1;
    const int quad  = lane >> 4;
    const int l15   = lane & 15;

    f32x4 acc[4][4] = {};

    const __half* Abase = W  + (size_t)(tileM * BM) * KP;
    const __half* Bbase = Xt + (size_t)(tileN * BN) * KP;

    const int kbeg = ks * KCH;
    const int kend = kbeg + KCH;
    for (int kb = kbeg; kb < kend; kb += BK) {
        __syncthreads();
#pragma unroll
        for (int i = 0; i < 2; ++i) {
            int cidx = t + i * 256;      // 0..511
            int row  = cidx >> 2;
            int seg  = cidx & 3;
            *(f16x8*)&As[row * LDW + seg * 8] =
                *(const f16x8*)(Abase + (size_t)row * KP + kb + seg * 8);
            *(f16x8*)&Bs[row * LDW + seg * 8] =
                *(const f16x8*)(Bbase + (size_t)row * KP + kb + seg * 8);
        }
        __syncthreads();

        f16x8 af[4], bf[4];
#pragma unroll
        for (int msub = 0; msub < 4; ++msub) {
            int m = warpM * 64 + msub * 16 + l15;
            af[msub] = *(const f16x8*)&As[m * LDW + quad * 8];
        }
#pragma unroll
        for (int nsub = 0; nsub < 4; ++nsub) {
            int n = warpN * 64 + nsub * 16 + l15;
            bf[nsub] = *(const f16x8*)&Bs[n * LDW + quad * 8];
        }
#pragma unroll
        for (int msub = 0; msub < 4; ++msub)
#pragma unroll
            for (int nsub = 0; nsub < 4; ++nsub)
                acc[msub][nsub] = __builtin_amdgcn_mfma_f32_16x16x32_f16(
                    af[msub], bf[nsub], acc[msub][nsub], 0, 0, 0);
    }

    // Epilogue: atomicAdd partial (C row m=(i0,i2), col=(i1,b)) scaled by invA.
    const int i1 = tileN;
#pragma unroll
    for (int nsub = 0; nsub < 4; ++nsub) {
        int bcol = warpN * 64 + nsub * 16 + l15;     // == b (0..127)
        float* ob = out + (size_t)bcol * OUTB + (size_t)i1 * PDIM;
#pragma unroll
        for (int msub = 0; msub < 4; ++msub) {
#pragma unroll
            for (int r = 0; r < 4; ++r) {
                int m = tileM * BM + warpM * 64 + msub * 16 + quad * 4 + r;
                if (m < PP) {
                    int i0 = m / PDIM;
                    int i2 = m - i0 * PDIM;
                    atomicAdd(&ob[(size_t)i0 * PP + i2],
                              acc[msub][nsub][r] * invA);
                }
            }
        }
    }
}

// ---------------- fallback (R6, proven ~151 us) ----------------

#define ROWW 47
#define PADL 7
#define BLK  384
#define NV   3
#define GRID 1280

typedef _Float16 h2v __attribute__((ext_vector_type(2)));

#if defined(__has_builtin)
#if __has_builtin(__builtin_amdgcn_fractf)
#define FRACTF(x) __builtin_amdgcn_fractf(x)
#endif
#endif
#ifndef FRACTF
#define FRACTF(x) ((x) - floorf(x))
#endif

__device__ __forceinline__ float fdot2u(unsigned int a, unsigned int b, float c)
{
    return __builtin_amdgcn_fdot2(__builtin_bit_cast(h2v, a),
                                  __builtin_bit_cast(h2v, b), c, false);
}

__global__ __launch_bounds__(BLK)
void fbp_adjoint_kernel(const float* __restrict__ x,
                        const float* __restrict__ angles,
                        float* __restrict__ out,
                        int nslice, float invA)
{
    __shared__ unsigned int dr[A_ * ROWW];
    __shared__ float2       cs_lds[A_];

    const int t = threadIdx.x;
    for (int j = t; j < A_; j += BLK) {
        float s, c;
        sincosf(angles[j], &s, &c);
        cs_lds[j] = make_float2(c, s);
    }

    float u0[NV], u2[NV];
#pragma unroll
    for (int nn = 0; nn < NV; ++nn) {
        int n  = t + nn * BLK;
        int nc = (n < PP) ? n : (PP - 1);
        int q0 = nc / PDIM;
        int q2 = nc - q0 * PDIM;
        u0[nn] = (float)(q0 - 16);
        u2[nn] = (float)(q2 - 16);
    }

    for (int slice = blockIdx.x; slice < nslice; slice += GRID) {
        if (slice != (int)blockIdx.x) __syncthreads();
        const int hb = slice / PDIM;
        const int i1 = slice - hb * PDIM;
        const int b0 = 2 * hb;
        const float* r0 = x + (size_t)b0 * (A_ * PP) + (size_t)i1 * PDIM;
        const float* r1 = r0 + (size_t)(A_ * PP);
        for (int e = t; e < A_ * ROWW; e += BLK) {
            int j = e / ROWW;
            int p = e - j * ROWW;
            int k = p - PADL;
            float f0 = 0.0f, f1 = 0.0f;
            if (k >= 0 && k < PDIM) {
                size_t o = (size_t)j * PP + k;
                f0 = r0[o];
                f1 = r1[o];
            }
            dr[e] = __builtin_bit_cast(unsigned int,
                        __halves2half2(__float2half_rn(f0), __float2half_rn(f1)));
        }
        __syncthreads();

        float a0[NV] = {0.0f, 0.0f, 0.0f};
        float a1[NV] = {0.0f, 0.0f, 0.0f};
#pragma unroll 2
        for (int j = 0; j < A_; ++j) {
            float2 cj = cs_lds[j];
            const unsigned int* base = &dr[j * ROWW];
#pragma unroll
            for (int nn = 0; nn < NV; ++nn) {
                float ixp = fmaf(u2[nn], cj.x, fmaf(u0[nn], cj.y, 23.0f));
                int   kp  = (int)ixp;
                float w1  = FRACTF(ixp);
                unsigned int wp = __builtin_bit_cast(unsigned int,
                                    __builtin_amdgcn_cvt_pkrtz(1.0f - w1, w1));
                unsigned int d0 = base[kp];
                unsigned int d1 = base[kp + 1];
                unsigned int p0 = __builtin_amdgcn_perm(d1, d0, 0x05040100u);
                unsigned int p1 = __builtin_amdgcn_perm(d1, d0, 0x07060302u);
                a0[nn] = fdot2u(p0, wp, a0[nn]);
                a1[nn] = fdot2u(p1, wp, a1[nn]);
            }
        }

        float* ob0 = out + (size_t)b0 * OUTB + (size_t)i1 * PDIM;
        float* ob1 = ob0 + (size_t)OUTB;
#pragma unroll
        for (int nn = 0; nn < NV; ++nn) {
            int n = t + nn * BLK;
            if (n < PP) {
                int q0 = n / PDIM;
                int q2 = n - q0 * PDIM;
                size_t o = (size_t)q0 * PP + q2;
                ob0[o] = a0[nn] * invA;
                ob1[o] = a1[nn] * invA;
            }
        }
    }
}

// ---------------- launch ----------------

extern "C" void kernel_launch(void* const* d_in, const int* in_sizes, int n_in,
                              void* d_out, int out_size, void* d_ws, size_t ws_size,
                              hipStream_t stream)
{
    const float* x      = (const float*)d_in[0];
    const float* angles = (const float*)d_in[1];
    float* out          = (float*)d_out;

    const int A = in_sizes[1];                    // 121
    const int B = in_sizes[0] / (A * PP);         // 128
    const float invA = 1.0f / (float)A;

    const size_t wBytes  = (size_t)MP * KP * sizeof(__half);         // 9.29 MB
    const size_t xtBytes = (size_t)(PDIM * B) * KP * sizeof(__half); // 34.1 MB

    if (ws_size >= wBytes + xtBytes && A == A_ && B == 128) {
        __half* W  = (__half*)d_ws;
        __half* Xt = (__half*)((char*)d_ws + wBytes);
        hipMemsetAsync(out, 0, (size_t)out_size * sizeof(float), stream);
        wfill_kernel<<<MP, 128, 0, stream>>>(angles, W);
        xt_kernel<<<PDIM * B, 256, 0, stream>>>(x, Xt);
        gemm_kernel<<<NT * KS * MT, 256, 0, stream>>>(W, Xt, out, invA);
    } else {
        const int nslice = (B / 2) * PDIM;
        dim3 grid(GRID < nslice ? GRID : nslice);
        fbp_adjoint_kernel<<<grid, BLK, 0, stream>>>(x, angles, out,
                                                     nslice, invA);
    }
}

// Round 9
// 193.475 us; speedup vs baseline: 2.7677x; 2.7677x over previous
//
#include <hip/hip_runtime.h>
#include <hip/hip_fp16.h>
#include <math.h>

// FBP adjoint as dense f16 MFMA GEMM.
//   out[b,i0,i1,i2] = (1/A) * sum_{j,k} W[(i0,i2),(j,k)] * x[b,j,i1,k]
// C[M=1089, N=4224(i1*128+b)] = W[MxK] . Xt[NxK]^T, K=3993 padded to 4032.
// R9: no split-K (R8's atomics serialized: 421us, WRITE 289MB). Fix R7's real
// problem (297 blocks = 1.16/CU, MfmaUtil 12%) with 64x64 tiles -> 1188 blocks
// (4.6/CU, ~19 waves/CU). Staging via global_load_lds width=16 (no ds_write
// issue slots, no VGPR round-trip) into pad-free LDS; bank conflicts broken by
// XOR-swizzling the 16B chunk index on the GLOBAL source (LDS dest stays
// lane-linear as global_load_lds requires); frag reads un-swizzle -> <=2-way.

#define PDIM 33
#define PP   1089
#define A_   121
#define K_   3993
#define KP   4032
#define MP   1152            // padded M (18*64)
#define MT2  18              // M tiles (64)
#define NT2  66              // N tiles (64) = 33 i1 * 2 b-halves
#define OUTB 35937           // 33*33*33

typedef _Float16 f16x8 __attribute__((ext_vector_type(8)));
typedef float    f32x4 __attribute__((ext_vector_type(4)));

typedef __attribute__((address_space(1))) const unsigned int* gp_t;
typedef __attribute__((address_space(3))) unsigned int*       lp_t;

// ---------------- fast path kernels ----------------

__global__ __launch_bounds__(128)
void wfill_kernel(const float* __restrict__ angles, __half* __restrict__ W)
{
    const int n = blockIdx.x;            // 0..1151
    const int t = threadIdx.x;
    __half* row = W + (size_t)n * KP;
    for (int e = t; e < KP; e += 128) row[e] = __float2half_rn(0.0f);
    __syncthreads();
    if (n >= PP || t >= A_) return;
    const int j  = t;
    const int i0 = n / PDIM;
    const int i2 = n - i0 * PDIM;
    float s, c;
    sincosf(angles[j], &s, &c);
    float ix = fmaf((float)(i2 - 16), c, fmaf((float)(i0 - 16), s, 16.0f));
    float fl = floorf(ix);
    int   k0 = (int)fl;
    float w1 = ix - fl;
    float w0 = 1.0f - w1;
    __half* seg = row + j * PDIM;
    if (k0 >= 0     && k0 < PDIM)     seg[k0]     = __float2half_rn(w0);
    if (k0 + 1 >= 0 && k0 + 1 < PDIM) seg[k0 + 1] = __float2half_rn(w1);
}

// Xt row n=(i1*128+b): x[b,:,i1,:] flattened (j,k) fp16, K-padded 0.
// Dword (2-half) stores via cvt_pkrtz.
__global__ __launch_bounds__(256)
void xt_kernel(const float* __restrict__ x, __half* __restrict__ Xt)
{
    const int n  = blockIdx.x;           // 0..4223
    const int i1 = n >> 7;
    const int b  = n & 127;
    const float* src = x + (size_t)b * (A_ * PP) + (size_t)i1 * PDIM;
    unsigned int* dst = (unsigned int*)(Xt + (size_t)n * KP);
    for (int e = threadIdx.x; e < KP / 2; e += 256) {
        int kk0 = 2 * e, kk1 = 2 * e + 1;
        float v0 = 0.0f, v1 = 0.0f;
        if (kk0 < K_) {
            int j = kk0 / PDIM, k = kk0 - j * PDIM;
            v0 = src[(size_t)j * PP + k];
        }
        if (kk1 < K_) {
            int j = kk1 / PDIM, k = kk1 - j * PDIM;
            v1 = src[(size_t)j * PP + k];
        }
        dst[e] = __builtin_bit_cast(unsigned int,
                     __builtin_amdgcn_cvt_pkrtz(v0, v1));
    }
}

// GEMM: C = W . Xt^T, 64x64 tile, BK=64, 4 waves (2x2), 32x32 per wave.
__global__ __launch_bounds__(256)
void gemm_kernel(const __half* __restrict__ W, const __half* __restrict__ Xt,
                 float* __restrict__ out, float invA)
{
    __shared__ _Float16 As[64 * 64];     // 8 KB, chunk-swizzled
    __shared__ _Float16 Bs[64 * 64];     // 8 KB

    const int blk   = blockIdx.x;
    const int tileN = blk / MT2;         // consecutive blocks share Xt panel
    const int tileM = blk - tileN * MT2;
    const int t     = threadIdx.x;
    const int lane  = t & 63;
    const int wave  = t >> 6;
    const int warpM = wave >> 1;
    const int warpN = wave & 1;
    const int quad  = lane >> 4;
    const int l15   = lane & 15;

    f32x4 acc[2][2] = {};

    const __half* Ab = W  + (size_t)(tileM * 64) * KP;
    const __half* Bb = Xt + (size_t)(tileN * 64) * KP;

    // Staging chunk geometry: chunk cidx (0..511) = 16B = (row=cidx>>3,
    // seg=cidx&7). Global k-seg fetched = seg ^ (row&7); LDS dest linear.
    int srow[2], ssego[2];
#pragma unroll
    for (int i = 0; i < 2; ++i) {
        int cidx = t + i * 256;
        int row  = cidx >> 3;
        int seg  = cidx & 7;
        srow[i]  = row;
        ssego[i] = (seg ^ (row & 7)) * 8;   // halves offset within K-slice
    }

    // Frag-read addresses (halves): row r, k-seg ks -> r*64 + (ks^(r&7))*8
    int arow[2], brow[2];
#pragma unroll
    for (int s = 0; s < 2; ++s) {
        arow[s] = warpM * 32 + s * 16 + l15;
        brow[s] = warpN * 32 + s * 16 + l15;
    }

    for (int kb = 0; kb < KP; kb += 64) {
        __syncthreads();
#pragma unroll
        for (int i = 0; i < 2; ++i) {
            const __half* ga = Ab + (size_t)srow[i] * KP + kb + ssego[i];
            const __half* gb = Bb + (size_t)srow[i] * KP + kb + ssego[i];
            __builtin_amdgcn_global_load_lds((gp_t)(const void*)ga,
                (lp_t)(void*)&As[(t + i * 256) * 8], 16, 0, 0);
            __builtin_amdgcn_global_load_lds((gp_t)(const void*)gb,
                (lp_t)(void*)&Bs[(t + i * 256) * 8], 16, 0, 0);
        }
        __syncthreads();

        f16x8 af[2][2], bf[2][2];
#pragma unroll
        for (int h = 0; h < 2; ++h) {
#pragma unroll
            for (int s = 0; s < 2; ++s) {
                int ks = h * 4 + quad;
                af[h][s] = *(const f16x8*)&As[arow[s] * 64 + ((ks ^ (arow[s] & 7)) * 8)];
                bf[h][s] = *(const f16x8*)&Bs[brow[s] * 64 + ((ks ^ (brow[s] & 7)) * 8)];
            }
        }
#pragma unroll
        for (int h = 0; h < 2; ++h)
#pragma unroll
            for (int ms = 0; ms < 2; ++ms)
#pragma unroll
                for (int ns = 0; ns < 2; ++ns)
                    acc[ms][ns] = __builtin_amdgcn_mfma_f32_16x16x32_f16(
                        af[h][ms], bf[h][ns], acc[ms][ns], 0, 0, 0);
    }

    // Epilogue: C row m=(i0,i2), col nglob=(i1*128+b); out[b,i0,i1,i2].
#pragma unroll
    for (int ns = 0; ns < 2; ++ns) {
        int nglob = tileN * 64 + warpN * 32 + ns * 16 + l15;
        int i1 = nglob >> 7;
        int b  = nglob & 127;
        float* ob = out + (size_t)b * OUTB + (size_t)i1 * PDIM;
#pragma unroll
        for (int ms = 0; ms < 2; ++ms) {
#pragma unroll
            for (int r = 0; r < 4; ++r) {
                int m = tileM * 64 + warpM * 32 + ms * 16 + quad * 4 + r;
                if (m < PP) {
                    int i0 = m / PDIM;
                    int i2 = m - i0 * PDIM;
                    ob[(size_t)i0 * PP + i2] = acc[ms][ns][r] * invA;
                }
            }
        }
    }
}

// ---------------- fallback (R6, proven ~151 us) ----------------

#define ROWW 47
#define PADL 7
#define BLK  384
#define NV   3
#define GRID 1280

typedef _Float16 h2v __attribute__((ext_vector_type(2)));

#if defined(__has_builtin)
#if __has_builtin(__builtin_amdgcn_fractf)
#define FRACTF(x) __builtin_amdgcn_fractf(x)
#endif
#endif
#ifndef FRACTF
#define FRACTF(x) ((x) - floorf(x))
#endif

__device__ __forceinline__ float fdot2u(unsigned int a, unsigned int b, float c)
{
    return __builtin_amdgcn_fdot2(__builtin_bit_cast(h2v, a),
                                  __builtin_bit_cast(h2v, b), c, false);
}

__global__ __launch_bounds__(BLK)
void fbp_adjoint_kernel(const float* __restrict__ x,
                        const float* __restrict__ angles,
                        float* __restrict__ out,
                        int nslice, float invA)
{
    __shared__ unsigned int dr[A_ * ROWW];
    __shared__ float2       cs_lds[A_];

    const int t = threadIdx.x;
    for (int j = t; j < A_; j += BLK) {
        float s, c;
        sincosf(angles[j], &s, &c);
        cs_lds[j] = make_float2(c, s);
    }

    float u0[NV], u2[NV];
#pragma unroll
    for (int nn = 0; nn < NV; ++nn) {
        int n  = t + nn * BLK;
        int nc = (n < PP) ? n : (PP - 1);
        int q0 = nc / PDIM;
        int q2 = nc - q0 * PDIM;
        u0[nn] = (float)(q0 - 16);
        u2[nn] = (float)(q2 - 16);
    }

    for (int slice = blockIdx.x; slice < nslice; slice += GRID) {
        if (slice != (int)blockIdx.x) __syncthreads();
        const int hb = slice / PDIM;
        const int i1 = slice - hb * PDIM;
        const int b0 = 2 * hb;
        const float* r0 = x + (size_t)b0 * (A_ * PP) + (size_t)i1 * PDIM;
        const float* r1 = r0 + (size_t)(A_ * PP);
        for (int e = t; e < A_ * ROWW; e += BLK) {
            int j = e / ROWW;
            int p = e - j * ROWW;
            int k = p - PADL;
            float f0 = 0.0f, f1 = 0.0f;
            if (k >= 0 && k < PDIM) {
                size_t o = (size_t)j * PP + k;
                f0 = r0[o];
                f1 = r1[o];
            }
            dr[e] = __builtin_bit_cast(unsigned int,
                        __halves2half2(__float2half_rn(f0), __float2half_rn(f1)));
        }
        __syncthreads();

        float a0[NV] = {0.0f, 0.0f, 0.0f};
        float a1[NV] = {0.0f, 0.0f, 0.0f};
#pragma unroll 2
        for (int j = 0; j < A_; ++j) {
            float2 cj = cs_lds[j];
            const unsigned int* base = &dr[j * ROWW];
#pragma unroll
            for (int nn = 0; nn < NV; ++nn) {
                float ixp = fmaf(u2[nn], cj.x, fmaf(u0[nn], cj.y, 23.0f));
                int   kp  = (int)ixp;
                float w1  = FRACTF(ixp);
                unsigned int wp = __builtin_bit_cast(unsigned int,
                                    __builtin_amdgcn_cvt_pkrtz(1.0f - w1, w1));
                unsigned int d0 = base[kp];
                unsigned int d1 = base[kp + 1];
                unsigned int p0 = __builtin_amdgcn_perm(d1, d0, 0x05040100u);
                unsigned int p1 = __builtin_amdgcn_perm(d1, d0, 0x07060302u);
                a0[nn] = fdot2u(p0, wp, a0[nn]);
                a1[nn] = fdot2u(p1, wp, a1[nn]);
            }
        }

        float* ob0 = out + (size_t)b0 * OUTB + (size_t)i1 * PDIM;
        float* ob1 = ob0 + (size_t)OUTB;
#pragma unroll
        for (int nn = 0; nn < NV; ++nn) {
            int n = t + nn * BLK;
            if (n < PP) {
                int q0 = n / PDIM;
                int q2 = n - q0 * PDIM;
                size_t o = (size_t)q0 * PP + q2;
                ob0[o] = a0[nn] * invA;
                ob1[o] = a1[nn] * invA;
            }
        }
    }
}

// ---------------- launch ----------------

extern "C" void kernel_launch(void* const* d_in, const int* in_sizes, int n_in,
                              void* d_out, int out_size, void* d_ws, size_t ws_size,
                              hipStream_t stream)
{
    const float* x      = (const float*)d_in[0];
    const float* angles = (const float*)d_in[1];
    float* out          = (float*)d_out;

    const int A = in_sizes[1];                    // 121
    const int B = in_sizes[0] / (A * PP);         // 128
    const float invA = 1.0f / (float)A;

    const size_t wBytes  = (size_t)MP * KP * sizeof(__half);         // 9.29 MB
    const size_t xtBytes = (size_t)(PDIM * B) * KP * sizeof(__half); // 34.1 MB

    if (ws_size >= wBytes + xtBytes && A == A_ && B == 128) {
        __half* W  = (__half*)d_ws;
        __half* Xt = (__half*)((char*)d_ws + wBytes);
        wfill_kernel<<<MP, 128, 0, stream>>>(angles, W);
        xt_kernel<<<PDIM * B, 256, 0, stream>>>(x, Xt);
        gemm_kernel<<<NT2 * MT2, 256, 0, stream>>>(W, Xt, out, invA);
    } else {
        const int nslice = (B / 2) * PDIM;
        dim3 grid(GRID < nslice ? GRID : nslice);
        fbp_adjoint_kernel<<<grid, BLK, 0, stream>>>(x, angles, out,
                                                     nslice, invA);
    }
}